// Round 6
// baseline (565.906 us; speedup 1.0000x reference)
//
#include <hip/hip_runtime.h>

// WeatherDifferentiatedAttention — MI355X bf16-MFMA implementation, round 7.
// Shapes: B=8 T=96 Nt=200 Nw=100 C=256 dh=64 H=4 hd=16; S=B*T=768.
// MFMA 16x16x32 bf16 layouts (HW-verified): A[m=lane&15][k=quad*8+j],
// B[n=lane&15][k=quad*8+j], D: col=lane&15, row=quad*4+reg.
// R3: fused attn_out+out_proj. R6: out_fused Ls-staged flush (ideal WRITE)
//   + resid prefetch. R5 lesson: 64B/row segments write-amplify 1.23x.
// R7: LN kernels rewritten as ln_stream_k — global_load_lds async staging
//   (32KB f32 tile, deep off-register queue -> Little's law satisfied;
//   reg-path capped at ~256B/wave in flight = the measured 1.07 TB/s wall).
//   Convert phase conflict-free (row-wise 16B/lane); MFMA+LN math identical.

#define DEV __device__ __forceinline__

typedef float  f32x4  __attribute__((ext_vector_type(4)));
typedef int    i32x4  __attribute__((ext_vector_type(4)));
typedef unsigned int u32x2 __attribute__((ext_vector_type(2)));
typedef __bf16 bf16x8 __attribute__((ext_vector_type(8)));

DEV f32x4 mfma_bf16(i32x4 a, i32x4 b, f32x4 c) {
  return __builtin_amdgcn_mfma_f32_16x16x32_bf16(
      __builtin_bit_cast(bf16x8, a), __builtin_bit_cast(bf16x8, b), c, 0, 0, 0);
}

DEV unsigned short f2b(float f) {
  unsigned int u = __builtin_bit_cast(unsigned int, f);
  u += 0x7FFFu + ((u >> 16) & 1u);   // round-to-nearest-even
  return (unsigned short)(u >> 16);
}

// async global->LDS, 16B per lane; gaddr per-lane, LDS dest = wave-uniform
// base + lane*16 (HW rule). Linear both sides (rule #21 safe).
DEV void gload16(const void* g, void* l) {
  __builtin_amdgcn_global_load_lds(
      (const __attribute__((address_space(1))) unsigned int*)(unsigned long long)g,
      (__attribute__((address_space(3))) unsigned int*)(unsigned int)(unsigned long long)l,
      16, 0, 0);
}

// ---------------- K0: convert the 5 weight matrices to bf16 in ws ----------
__global__ void cvt_weights_k(const float* __restrict__ w0, const float* __restrict__ w1,
                              const float* __restrict__ w2, const float* __restrict__ w3,
                              const float* __restrict__ w4, unsigned short* __restrict__ out) {
  int i = blockIdx.x * 256 + threadIdx.x;
  int idx = i;
  float v;
  if (idx < 16384) v = w0[idx];
  else if ((idx -= 16384) < 16384) v = w1[idx];
  else if ((idx -= 16384) < 12288) v = w2[idx];
  else if ((idx -= 12288) < 4096)  v = w3[idx];
  else { idx -= 4096; if (idx >= 16384) return; v = w4[idx]; }
  out[i] = f2b(v);
}

// ---------------- K1/K2: streaming LayerNorm(X*W^T + b) --------------------
// X: [rows][256] f32 (rows % 32 == 0). out: bf16 [rows][64].
// STAGE: 32-row f32 tile via async global_load_lds (32 KB in flight/block).
// CONVERT: per-row 64x16B reads (conflict-free), f2b, bf16 tile (+8 pad).
// MFMA+LN: identical math/order to the previous MODE-1 path.
__global__ __launch_bounds__(128) void ln_stream_k(
    const float* __restrict__ x,
    const unsigned short* __restrict__ Wb,   // [64][256] bf16
    const float* __restrict__ bias,
    const float* __restrict__ gamma, const float* __restrict__ beta,
    unsigned short* __restrict__ out) {
  __shared__ __align__(16) float fs[32][256];           // 32 KB staged f32
  __shared__ __align__(16) unsigned short xs[32][264];  // bf16 tile (+8 pad)
  const int tid = threadIdx.x;
  const int lane = tid & 63, w = tid >> 6;
  const long row0 = (long)blockIdx.x * 32;

  // STAGE: wave w stages rows w*16+i; each instr copies 1 KB (one row)
  {
    const char* g = (const char*)(x + row0 * 256);
#pragma unroll
    for (int i = 0; i < 16; ++i) {
      const int r = w * 16 + i;
      gload16(g + (size_t)r * 1024 + (size_t)lane * 16, &fs[r][0]);
    }
  }
  __builtin_amdgcn_s_waitcnt(0);
  __syncthreads();

  // CONVERT: wave w converts its own rows (same-wave produce->consume below)
#pragma unroll
  for (int i = 0; i < 16; ++i) {
    const int r = w * 16 + i;
    f32x4 v = *(const f32x4*)((const char*)&fs[r][0] + lane * 16);
    unsigned int lo = (unsigned int)f2b(v[0]) | ((unsigned int)f2b(v[1]) << 16);
    unsigned int hi = (unsigned int)f2b(v[2]) | ((unsigned int)f2b(v[3]) << 16);
    *(u32x2*)((char*)&xs[r][0] + lane * 8) = (u32x2){lo, hi};
  }
  __builtin_amdgcn_s_waitcnt(0);   // drain ds_writes before cross-lane reads

  const int m = lane & 15, quad = lane >> 4;
  const int arow = w * 16 + m;

  float accs[4][4];
#pragma unroll
  for (int ct = 0; ct < 4; ++ct) {
    f32x4 acc = {0.f, 0.f, 0.f, 0.f};
    const unsigned short* wp = Wb + (ct * 16 + m) * 256 + quad * 8;
#pragma unroll
    for (int ks = 0; ks < 8; ++ks) {
      i32x4 a = *(const i32x4*)(&xs[arow][ks * 32 + quad * 8]);
      i32x4 b = *(const i32x4*)(wp + ks * 32);
      acc = mfma_bf16(a, b, acc);
    }
    float bv = bias[ct * 16 + m];
#pragma unroll
    for (int rg = 0; rg < 4; ++rg) accs[ct][rg] = acc[rg] + bv;
  }
  float g[4], bb[4];
#pragma unroll
  for (int ct = 0; ct < 4; ++ct) { g[ct] = gamma[ct * 16 + m]; bb[ct] = beta[ct * 16 + m]; }
#pragma unroll
  for (int rg = 0; rg < 4; ++rg) {
    float s = accs[0][rg] + accs[1][rg] + accs[2][rg] + accs[3][rg];
#pragma unroll
    for (int msk = 1; msk < 16; msk <<= 1) s += __shfl_xor(s, msk, 64);
    float mu = s * (1.0f / 64.0f);
    float vs = 0.f;
#pragma unroll
    for (int ct = 0; ct < 4; ++ct) { float d = accs[ct][rg] - mu; vs += d * d; }
#pragma unroll
    for (int msk = 1; msk < 16; msk <<= 1) vs += __shfl_xor(vs, msk, 64);
    float inv = rsqrtf(vs * (1.0f / 64.0f) + 1e-5f);
    long row = row0 + w * 16 + quad * 4 + rg;
#pragma unroll
    for (int ct = 0; ct < 4; ++ct) {
      float y = (accs[ct][rg] - mu) * inv * g[ct] + bb[ct];
      out[row * 64 + ct * 16 + m] = f2b(y);
    }
  }
}

// ---------------- generic MFMA affine kernel (no LDS), MODE 0 only ---------
// out = bf16(X*W^T + b), X bf16
template <int CIN, int COUT>
__global__ __launch_bounds__(256) void affine_k(
    const void* __restrict__ xin,
    const unsigned short* __restrict__ Wb,   // [COUT][CIN] bf16
    const float* __restrict__ bias,
    void* __restrict__ outp) {
  const int tid = threadIdx.x;
  const long row0 = (long)blockIdx.x * 64;
  const int lane = tid & 63, wv = tid >> 6;
  const int m = lane & 15, quad = lane >> 4;
  const long grow = row0 + wv * 16 + m;

  constexpr int KS = CIN / 32;
  i32x4 a_reg[KS];
  const unsigned short* xb = (const unsigned short*)xin + grow * CIN + quad * 8;
#pragma unroll
  for (int ks = 0; ks < KS; ++ks)
    a_reg[ks] = *(const i32x4*)(xb + ks * 32);

#pragma unroll
  for (int ct = 0; ct < COUT / 16; ++ct) {
    f32x4 acc = {0.f, 0.f, 0.f, 0.f};
    const unsigned short* wp = Wb + (ct * 16 + m) * CIN + quad * 8;
#pragma unroll
    for (int ks = 0; ks < KS; ++ks) {
      i32x4 b = *(const i32x4*)(wp + ks * 32);
      acc = mfma_bf16(a_reg[ks], b, acc);
    }
    int col = ct * 16 + m;
    float bv = bias[col];
    unsigned short* ob = (unsigned short*)outp;
#pragma unroll
    for (int rg = 0; rg < 4; ++rg) {
      long row = row0 + wv * 16 + quad * 4 + rg;
      ob[row * COUT + col] = f2b(acc[rg] + bv);
    }
  }
}

// ---------------- K6: fused attn_out + out_proj + residual -----------------
// a = bf16(o @ Wao^T + bao)   (stays in LDS, identical numerics to old path)
// out = f32(a @ Wop^T + bop + resid). Loads of o are LDS-staged (coalesced
// 16B/lane sequential); output flushed via per-wave Ls stage so resid reads
// and out writes are float4 row-contiguous 256B segments (measured-ideal
// WRITE_SIZE). Resid for each cg is prefetched before the cg's MFMA phase.
__global__ __launch_bounds__(256) void out_fused_k(
    const unsigned short* __restrict__ o,     // [153600][64] bf16
    const unsigned short* __restrict__ Wao,   // [64][64] bf16
    const float* __restrict__ bao,
    const unsigned short* __restrict__ Wop,   // [256][64] bf16
    const float* __restrict__ bop,
    const float* __restrict__ resid,          // [153600][256] f32
    float* __restrict__ out) {                // [153600][256] f32
  __shared__ __align__(16) unsigned short xs[64][72];
  __shared__ __align__(16) unsigned short as[64][72];
  __shared__ __align__(16) float Ls[4][16][68];   // per-wave f32 stage (+4 pad)
  const int tid = threadIdx.x;
  const long row0 = (long)blockIdx.x * 64;

  {
    const i32x4* xb = (const i32x4*)o + (size_t)row0 * 8;
    for (int i = tid; i < 512; i += 256) {
      int r = i >> 3, c = i & 7;
      *(i32x4*)&xs[r][c * 8] = xb[i];
    }
  }
  __syncthreads();

  const int lane = tid & 63, wv = tid >> 6;
  const int m = lane & 15, quad = lane >> 4;
  const int arow = wv * 16 + m;

  i32x4 af0 = *(const i32x4*)&xs[arow][quad * 8];
  i32x4 af1 = *(const i32x4*)&xs[arow][32 + quad * 8];

  // stage 1: a-tile (each wave computes + consumes its own 16 rows)
#pragma unroll
  for (int ct = 0; ct < 4; ++ct) {
    const unsigned short* wp = Wao + (ct * 16 + m) * 64 + quad * 8;
    f32x4 acc = {0.f, 0.f, 0.f, 0.f};
    acc = mfma_bf16(af0, *(const i32x4*)wp, acc);
    acc = mfma_bf16(af1, *(const i32x4*)(wp + 32), acc);
    float bv = bao[ct * 16 + m];
#pragma unroll
    for (int rg = 0; rg < 4; ++rg)
      as[wv * 16 + quad * 4 + rg][ct * 16 + m] = f2b(acc[rg] + bv);
  }
  __builtin_amdgcn_s_waitcnt(0);

  i32x4 bf0 = *(const i32x4*)&as[arow][quad * 8];
  i32x4 bf1 = *(const i32x4*)&as[arow][32 + quad * 8];

  const float4* residv = (const float4*)resid;
  float4* outv = (float4*)out;

  // flush-pattern addresses for this lane (same for every cg, offset by cg*16)
  size_t gibase[4];
#pragma unroll
  for (int i = 0; i < 4; ++i) {
    int idx = lane + i * 64;                 // 0..255 within wave tile
    int r = idx >> 4, c4 = idx & 15;
    gibase[i] = (size_t)(row0 + wv * 16 + r) * 64 + c4;
  }

  // stage 2: 4 column-groups of 64; resid prefetched before MFMA phase,
  // f32 result staged in LDS, flushed as row-contiguous float4.
#pragma unroll
  for (int cg = 0; cg < 4; ++cg) {
    float4 rv[4];
#pragma unroll
    for (int i = 0; i < 4; ++i) rv[i] = residv[gibase[i] + cg * 16];  // issue early

#pragma unroll
    for (int c2 = 0; c2 < 4; ++c2) {
      int col = cg * 64 + c2 * 16 + m;
      const unsigned short* wp = Wop + col * 64 + quad * 8;
      f32x4 acc = {0.f, 0.f, 0.f, 0.f};
      acc = mfma_bf16(bf0, *(const i32x4*)wp, acc);
      acc = mfma_bf16(bf1, *(const i32x4*)(wp + 32), acc);
      float bv = bop[col];
#pragma unroll
      for (int rg = 0; rg < 4; ++rg)
        Ls[wv][quad * 4 + rg][c2 * 16 + m] = acc[rg] + bv;
    }
    __builtin_amdgcn_s_waitcnt(0);
#pragma unroll
    for (int i = 0; i < 4; ++i) {
      int idx = lane + i * 64;
      int r = idx >> 4, c4 = idx & 15;
      f32x4 sv = *(const f32x4*)&Ls[wv][r][c4 * 4];
      float4 ov;
      ov.x = sv[0] + rv[i].x; ov.y = sv[1] + rv[i].y;
      ov.z = sv[2] + rv[i].z; ov.w = sv[3] + rv[i].w;
      outv[gibase[i] + cg * 16] = ov;
    }
    __builtin_amdgcn_s_waitcnt(0);   // reads drained before next cg overwrites Ls
  }
}

// ---------------- K3: cross attention (per bt block) -----------------------
// logits = ht @ hw^T / 8 ; softmax over m (Nw=100) ; x = attn @ hw
__global__ __launch_bounds__(256) void cross_attn_k(
    const unsigned short* __restrict__ ht,   // [768*200][64]
    const unsigned short* __restrict__ hw,   // [768*100][64]
    unsigned short* __restrict__ xout) {     // [768*200][64]
  const int bt = blockIdx.x;
  const int tid = threadIdx.x;
  __shared__ __align__(16) unsigned short Kl[112][72];     // hw rows, rows>=100 zero
  __shared__ __align__(16) unsigned short VT2[64][136];    // hw^T [d][m], zero pad
  __shared__ __align__(16) unsigned short P2[4][16][136];  // per-wave prob tile

  const i32x4 z4 = {0, 0, 0, 0};
  {
    i32x4* p0 = (i32x4*)&Kl[0][0];
    for (int i = tid; i < 1008; i += 256) p0[i] = z4;
    i32x4* p1 = (i32x4*)&VT2[0][0];
    for (int i = tid; i < 1088; i += 256) p1[i] = z4;
    i32x4* p2 = (i32x4*)&P2[0][0][0];
    for (int i = tid; i < 1088; i += 256) p2[i] = z4;
  }
  __syncthreads();
  {
    const unsigned short* wbase = hw + (size_t)bt * 100 * 64;
    for (int i = tid; i < 800; i += 256) {
      int r = i >> 3, c = (i & 7) * 8;
      i32x4 w = *(const i32x4*)(wbase + (size_t)r * 64 + c);
      *(i32x4*)&Kl[r][c] = w;
      unsigned short tmp[8];
      __builtin_memcpy(tmp, &w, 16);
#pragma unroll
      for (int j = 0; j < 8; ++j) VT2[c + j][r] = tmp[j];
    }
  }
  __syncthreads();

  const int lane = tid & 63, wv = tid >> 6;
  const int m = lane & 15, quad = lane >> 4;

  i32x4 kf[7][2];
#pragma unroll
  for (int mt = 0; mt < 7; ++mt)
#pragma unroll
    for (int ks = 0; ks < 2; ++ks)
      kf[mt][ks] = *(const i32x4*)&Kl[mt * 16 + m][ks * 32 + quad * 8];

  for (int c = wv; c < 13; c += 4) {
    const int n0 = c * 16;
    const unsigned short* ap = ht + ((size_t)bt * 200 + n0 + m) * 64 + quad * 8;
    i32x4 a0 = *(const i32x4*)ap;
    i32x4 a1 = *(const i32x4*)(ap + 32);

    float s[7][4];
#pragma unroll
    for (int mt = 0; mt < 7; ++mt) {
      f32x4 acc = mfma_bf16(a0, kf[mt][0], (f32x4){0.f, 0.f, 0.f, 0.f});
      acc = mfma_bf16(a1, kf[mt][1], acc);
#pragma unroll
      for (int rg = 0; rg < 4; ++rg) s[mt][rg] = acc[rg];
    }
#pragma unroll
    for (int rg = 0; rg < 4; ++rg)
      s[6][rg] = (m < 4) ? s[6][rg] : -3.0e38f;   // keys 96..99 valid, 100..111 masked

    float S[4];
#pragma unroll
    for (int rg = 0; rg < 4; ++rg) {
      float mx = s[0][rg];
#pragma unroll
      for (int mt = 1; mt < 7; ++mt) mx = fmaxf(mx, s[mt][rg]);
#pragma unroll
      for (int msk = 1; msk < 16; msk <<= 1) mx = fmaxf(mx, __shfl_xor(mx, msk, 64));
      float sum = 0.f;
#pragma unroll
      for (int mt = 0; mt < 7; ++mt) {
        float p = __expf((s[mt][rg] - mx) * 0.125f);
        s[mt][rg] = p; sum += p;
      }
#pragma unroll
      for (int msk = 1; msk < 16; msk <<= 1) sum += __shfl_xor(sum, msk, 64);
      S[rg] = sum;
    }
#pragma unroll
    for (int mt = 0; mt < 7; ++mt)
#pragma unroll
      for (int rg = 0; rg < 4; ++rg)
        P2[wv][quad * 4 + rg][mt * 16 + m] = f2b(s[mt][rg]);
    __builtin_amdgcn_s_waitcnt(0);

    i32x4 pa[4];
#pragma unroll
    for (int ks = 0; ks < 4; ++ks)
      pa[ks] = *(const i32x4*)&P2[wv][m][ks * 32 + quad * 8];
    float rs[4];
#pragma unroll
    for (int rg = 0; rg < 4; ++rg) rs[rg] = __fdividef(1.0f, S[rg]);

#pragma unroll
    for (int ct = 0; ct < 4; ++ct) {
      f32x4 acc = {0.f, 0.f, 0.f, 0.f};
#pragma unroll
      for (int ks = 0; ks < 4; ++ks) {
        i32x4 b = *(const i32x4*)&VT2[ct * 16 + m][ks * 32 + quad * 8];
        acc = mfma_bf16(pa[ks], b, acc);
      }
#pragma unroll
      for (int rg = 0; rg < 4; ++rg) {
        int n = n0 + quad * 4 + rg;
        if (n < 200)
          xout[((size_t)bt * 200 + n) * 64 + ct * 16 + m] = f2b(acc[rg] * rs[rg]);
      }
    }
  }
}

// ---------------- K5: self attention (per bt,head block) -------------------
// scores = q@k^T/4 over hd=16; K padded 16->32: A-quads 2,3 are zero, so the
// B garbage read there (finite) contributes 0. XCD swizzle keeps the 4 heads
// of a bt on one XCD for L2 sharing of qkv rows.
__global__ __launch_bounds__(256) void self_attn_k(
    const unsigned short* __restrict__ qkv,  // [768*200][192] (q|k|v)
    unsigned short* __restrict__ o) {        // [768*200][64]
  const int g = blockIdx.x;
  const int bt = ((g >> 5) << 3) | (g & 7);
  const int h = (g >> 3) & 3;
  const int tid = threadIdx.x;

  __shared__ __align__(16) unsigned short Kz[212][24];    // k slice, pad cols+rows zero
  __shared__ __align__(16) unsigned short VT[16][232];    // v^T [d][m], zero pad
  __shared__ __align__(16) unsigned short P[4][16][232];  // per-wave prob tile

  const i32x4 z4 = {0, 0, 0, 0};
  {
    i32x4* p0 = (i32x4*)&Kz[0][0];
    for (int i = tid; i < 636; i += 256) p0[i] = z4;
    i32x4* p1 = (i32x4*)&VT[0][0];
    for (int i = tid; i < 464; i += 256) p1[i] = z4;
    i32x4* p2 = (i32x4*)&P[0][0][0];
    for (int i = tid; i < 1856; i += 256) p2[i] = z4;
  }
  __syncthreads();
  {
    const unsigned short* kb = qkv + (size_t)bt * 200 * 192 + 64 + h * 16;
    const unsigned short* vb = kb + 64;
    for (int i = tid; i < 400; i += 256) {
      int r = i >> 1, c = (i & 1) * 8;
      *(i32x4*)&Kz[r][c] = *(const i32x4*)(kb + (size_t)r * 192 + c);
      i32x4 vv = *(const i32x4*)(vb + (size_t)r * 192 + c);
      unsigned short tmp[8];
      __builtin_memcpy(tmp, &vv, 16);
#pragma unroll
      for (int j = 0; j < 8; ++j) VT[c + j][r] = tmp[j];
    }
  }
  __syncthreads();

  const int lane = tid & 63, wv = tid >> 6;
  const int m = lane & 15, quad = lane >> 4;
  const bool kreal = quad < 2;

  i32x4 kf[13];
#pragma unroll
  for (int mt = 0; mt < 13; ++mt)
    kf[mt] = *(const i32x4*)&Kz[mt * 16 + m][quad * 8];

  const unsigned short* qb = qkv + (size_t)bt * 200 * 192 + h * 16;

  for (int c = wv; c < 13; c += 4) {
    const int n0 = c * 16;
    i32x4 a = kreal ? *(const i32x4*)(qb + (size_t)(n0 + m) * 192 + quad * 8) : z4;

    float s[13][4];
#pragma unroll
    for (int mt = 0; mt < 13; ++mt) {
      f32x4 acc = mfma_bf16(a, kf[mt], (f32x4){0.f, 0.f, 0.f, 0.f});
#pragma unroll
      for (int rg = 0; rg < 4; ++rg) s[mt][rg] = acc[rg];
    }
#pragma unroll
    for (int rg = 0; rg < 4; ++rg)
      s[12][rg] = (m < 8) ? s[12][rg] : -3.0e38f;   // keys 192..199 valid, 200..207 masked

    float S[4];
#pragma unroll
    for (int rg = 0; rg < 4; ++rg) {
      float mx = s[0][rg];
#pragma unroll
      for (int mt = 1; mt < 13; ++mt) mx = fmaxf(mx, s[mt][rg]);
#pragma unroll
      for (int msk = 1; msk < 16; msk <<= 1) mx = fmaxf(mx, __shfl_xor(mx, msk, 64));
      float sum = 0.f;
#pragma unroll
      for (int mt = 0; mt < 13; ++mt) {
        float p = __expf((s[mt][rg] - mx) * 0.25f);
        s[mt][rg] = p; sum += p;
      }
#pragma unroll
      for (int msk = 1; msk < 16; msk <<= 1) sum += __shfl_xor(sum, msk, 64);
      S[rg] = sum;
    }
#pragma unroll
    for (int mt = 0; mt < 13; ++mt)
#pragma unroll
      for (int rg = 0; rg < 4; ++rg)
        P[wv][quad * 4 + rg][mt * 16 + m] = f2b(s[mt][rg]);
    __builtin_amdgcn_s_waitcnt(0);

    f32x4 acc2 = {0.f, 0.f, 0.f, 0.f};
#pragma unroll
    for (int ks = 0; ks < 7; ++ks) {
      i32x4 pa = *(const i32x4*)&P[wv][m][ks * 32 + quad * 8];
      i32x4 vb2 = *(const i32x4*)&VT[m][ks * 32 + quad * 8];
      acc2 = mfma_bf16(pa, vb2, acc2);
    }
#pragma unroll
    for (int rg = 0; rg < 4; ++rg) {
      int n = n0 + quad * 4 + rg;
      if (n < 200)
        o[((size_t)bt * 200 + n) * 64 + h * 16 + m] = f2b(__fdividef(acc2[rg], S[rg]));
    }
  }
}

// ---------------- launch ----------------------------------------------------
extern "C" void kernel_launch(void* const* d_in, const int* in_sizes, int n_in,
                              void* d_out, int out_size, void* d_ws, size_t ws_size,
                              hipStream_t stream) {
  const float* turbine    = (const float*)d_in[0];
  const float* weather    = (const float*)d_in[1];
  const float* b_t_lin    = (const float*)d_in[3];
  const float* b_w_lin    = (const float*)d_in[5];
  const float* ln_t_g     = (const float*)d_in[6];
  const float* ln_t_b     = (const float*)d_in[7];
  const float* ln_w_g     = (const float*)d_in[8];
  const float* ln_w_b     = (const float*)d_in[9];
  const float* in_proj_b  = (const float*)d_in[11];
  const float* attn_out_b = (const float*)d_in[13];
  const float* out_proj_b = (const float*)d_in[15];

  unsigned short* ws  = (unsigned short*)d_ws;
  unsigned short* ht  = ws + 0;          //  9,830,400 (153600 x 64)
  unsigned short* hw  = ws + 9830400;    //  4,915,200 ( 76800 x 64)
  unsigned short* x   = ws + 14745600;   //  9,830,400
  unsigned short* qkv = ws + 24576000;   // 29,491,200 (153600 x 192)
  unsigned short* o   = ws + 0;          // alias ht (dead after cross_attn)
  unsigned short* wb  = ws + 54067200;   // 65,536 bf16 weights
  unsigned short* wtb = wb;
  unsigned short* wwb = wb + 16384;
  unsigned short* ipb = wb + 32768;
  unsigned short* aob = wb + 45056;
  unsigned short* opb = wb + 49152;

  cvt_weights_k<<<256, 256, 0, stream>>>((const float*)d_in[2], (const float*)d_in[4],
                                         (const float*)d_in[10], (const float*)d_in[12],
                                         (const float*)d_in[14], wb);
  ln_stream_k<<<4800, 128, 0, stream>>>(turbine, wtb, b_t_lin, ln_t_g, ln_t_b, ht);
  ln_stream_k<<<2400, 128, 0, stream>>>(weather, wwb, b_w_lin, ln_w_g, ln_w_b, hw);
  cross_attn_k<<<768, 256, 0, stream>>>(ht, hw, x);
  affine_k<64, 192><<<2400, 256, 0, stream>>>(
      x, ipb, in_proj_b, qkv);
  self_attn_k<<<3072, 256, 0, stream>>>(qkv, o);
  out_fused_k<<<2400, 256, 0, stream>>>(
      o, aob, attn_out_b, opb, out_proj_b, turbine, (float*)d_out);
}

// Round 7
// 545.358 us; speedup vs baseline: 1.0377x; 1.0377x over previous
//
#include <hip/hip_runtime.h>

// WeatherDifferentiatedAttention — MI355X bf16-MFMA implementation, round 8.
// Shapes: B=8 T=96 Nt=200 Nw=100 C=256 dh=64 H=4 hd=16; S=B*T=768.
// MFMA 16x16x32 bf16 layouts (HW-verified): A[m=lane&15][k=quad*8+j],
// B[n=lane&15][k=quad*8+j], D: col=lane&15, row=quad*4+reg.
// R3: fused attn_out+out_proj. R5 lesson: sub-128B/row write segments
//   amplify WRITE_SIZE (measured 1.23x at 64B). R6: out_fused Ls-staged
//   flush + resid prefetch (best total 557.6). R7 ln_stream: neutral ->
//   reverted to R6 affine LN.
// R8: qkv projection fused INTO cross_attn (cross_qkv_k): x never touches
//   global; qkv written head-major [bt][h][200][48] with lane-consecutive
//   chunks (no write amp); self_attn reads dense 96B rows. Removes the
//   affine<64,192> dispatch + x roundtrip entirely. Bit-identical numerics.

#define DEV __device__ __forceinline__

typedef float  f32x4  __attribute__((ext_vector_type(4)));
typedef int    i32x4  __attribute__((ext_vector_type(4)));
typedef unsigned int u32x2 __attribute__((ext_vector_type(2)));
typedef __bf16 bf16x8 __attribute__((ext_vector_type(8)));

DEV f32x4 mfma_bf16(i32x4 a, i32x4 b, f32x4 c) {
  return __builtin_amdgcn_mfma_f32_16x16x32_bf16(
      __builtin_bit_cast(bf16x8, a), __builtin_bit_cast(bf16x8, b), c, 0, 0, 0);
}

DEV unsigned short f2b(float f) {
  unsigned int u = __builtin_bit_cast(unsigned int, f);
  u += 0x7FFFu + ((u >> 16) & 1u);   // round-to-nearest-even
  return (unsigned short)(u >> 16);
}

// ---------------- K0: convert the 5 weight matrices to bf16 in ws ----------
__global__ void cvt_weights_k(const float* __restrict__ w0, const float* __restrict__ w1,
                              const float* __restrict__ w2, const float* __restrict__ w3,
                              const float* __restrict__ w4, unsigned short* __restrict__ out) {
  int i = blockIdx.x * 256 + threadIdx.x;
  int idx = i;
  float v;
  if (idx < 16384) v = w0[idx];
  else if ((idx -= 16384) < 16384) v = w1[idx];
  else if ((idx -= 16384) < 12288) v = w2[idx];
  else if ((idx -= 12288) < 4096)  v = w3[idx];
  else { idx -= 4096; if (idx >= 16384) return; v = w4[idx]; }
  out[i] = f2b(v);
}

// ---------------- K1/K2: LayerNorm(X*W^T + b) (R6-measured path) -----------
template <int CIN>
__global__ __launch_bounds__(256) void ln_affine_k(
    const float* __restrict__ xin,
    const unsigned short* __restrict__ Wb,   // [64][CIN] bf16
    const float* __restrict__ bias,
    const float* __restrict__ gamma, const float* __restrict__ beta,
    unsigned short* __restrict__ outp) {
  const int tid = threadIdx.x;
  const long row0 = (long)blockIdx.x * 64;
  const int lane = tid & 63, wv = tid >> 6;
  const int m = lane & 15, quad = lane >> 4;
  const long grow = row0 + wv * 16 + m;

  constexpr int KS = CIN / 32;
  i32x4 a_reg[KS];
  {
    const float* xf = xin + grow * CIN + quad * 8;
    float4 v0[KS], v1[KS];
#pragma unroll
    for (int ks = 0; ks < KS; ++ks) {
      v0[ks] = *(const float4*)(xf + ks * 32);
      v1[ks] = *(const float4*)(xf + ks * 32 + 4);
    }
#pragma unroll
    for (int ks = 0; ks < KS; ++ks) {
      unsigned int p0 = (unsigned int)f2b(v0[ks].x) | ((unsigned int)f2b(v0[ks].y) << 16);
      unsigned int p1 = (unsigned int)f2b(v0[ks].z) | ((unsigned int)f2b(v0[ks].w) << 16);
      unsigned int p2 = (unsigned int)f2b(v1[ks].x) | ((unsigned int)f2b(v1[ks].y) << 16);
      unsigned int p3 = (unsigned int)f2b(v1[ks].z) | ((unsigned int)f2b(v1[ks].w) << 16);
      a_reg[ks] = (i32x4){(int)p0, (int)p1, (int)p2, (int)p3};
    }
  }

  float accs[4][4];
#pragma unroll
  for (int ct = 0; ct < 4; ++ct) {
    f32x4 acc = {0.f, 0.f, 0.f, 0.f};
    const unsigned short* wp = Wb + (ct * 16 + m) * CIN + quad * 8;
#pragma unroll
    for (int ks = 0; ks < KS; ++ks) {
      i32x4 b = *(const i32x4*)(wp + ks * 32);
      acc = mfma_bf16(a_reg[ks], b, acc);
    }
    float bv = bias[ct * 16 + m];
#pragma unroll
    for (int rg = 0; rg < 4; ++rg) accs[ct][rg] = acc[rg] + bv;
  }
  float g[4], bb[4];
#pragma unroll
  for (int ct = 0; ct < 4; ++ct) { g[ct] = gamma[ct * 16 + m]; bb[ct] = beta[ct * 16 + m]; }
#pragma unroll
  for (int rg = 0; rg < 4; ++rg) {
    float s = accs[0][rg] + accs[1][rg] + accs[2][rg] + accs[3][rg];
#pragma unroll
    for (int msk = 1; msk < 16; msk <<= 1) s += __shfl_xor(s, msk, 64);
    float mu = s * (1.0f / 64.0f);
    float vs = 0.f;
#pragma unroll
    for (int ct = 0; ct < 4; ++ct) { float d = accs[ct][rg] - mu; vs += d * d; }
#pragma unroll
    for (int msk = 1; msk < 16; msk <<= 1) vs += __shfl_xor(vs, msk, 64);
    float inv = rsqrtf(vs * (1.0f / 64.0f) + 1e-5f);
    long row = row0 + wv * 16 + quad * 4 + rg;
#pragma unroll
    for (int ct = 0; ct < 4; ++ct) {
      float y = (accs[ct][rg] - mu) * inv * g[ct] + bb[ct];
      outp[row * 64 + ct * 16 + m] = f2b(y);
    }
  }
}

// ---------------- K3: cross attention + qkv projection (per bt) ------------
// logits = ht @ hw^T / 8 ; softmax ; x = attn @ hw (kept in LDS only);
// qkv = x @ Wip^T + bip, written head-major: qkvh[bt][h][200][48] where a
// row is q(16)|k(16)|v(16). Flush uses lane-consecutive 16B chunks.
__global__ __launch_bounds__(256) void cross_qkv_k(
    const unsigned short* __restrict__ ht,   // [768*200][64]
    const unsigned short* __restrict__ hw,   // [768*100][64]
    const unsigned short* __restrict__ Wip,  // [192][64] bf16
    const float* __restrict__ bip,           // [192]
    unsigned short* __restrict__ qkvh) {     // [768][4][200][48]
  const int bt = blockIdx.x;
  const int tid = threadIdx.x;
  __shared__ __align__(16) unsigned short Kl[112][72];    // hw rows, >=100 zero
  __shared__ __align__(16) unsigned short VT2[64][136];   // hw^T, zero pad
  __shared__ __align__(16) unsigned short PQ[4][16][200]; // P tile / qkv tile
  __shared__ __align__(16) unsigned short XT[4][16][72];  // per-wave x tile

  const i32x4 z4 = {0, 0, 0, 0};
  {
    i32x4* p0 = (i32x4*)&Kl[0][0];
    for (int i = tid; i < 1008; i += 256) p0[i] = z4;
    i32x4* p1 = (i32x4*)&VT2[0][0];
    for (int i = tid; i < 1088; i += 256) p1[i] = z4;
    i32x4* p2 = (i32x4*)&PQ[0][0][0];
    for (int i = tid; i < 1600; i += 256) p2[i] = z4;
  }
  __syncthreads();
  {
    const unsigned short* wbase = hw + (size_t)bt * 100 * 64;
    for (int i = tid; i < 800; i += 256) {
      int r = i >> 3, c = (i & 7) * 8;
      i32x4 w = *(const i32x4*)(wbase + (size_t)r * 64 + c);
      *(i32x4*)&Kl[r][c] = w;
      unsigned short tmp[8];
      __builtin_memcpy(tmp, &w, 16);
#pragma unroll
      for (int j = 0; j < 8; ++j) VT2[c + j][r] = tmp[j];
    }
  }
  __syncthreads();

  const int lane = tid & 63, wv = tid >> 6;
  const int m = lane & 15, quad = lane >> 4;

  i32x4 kf[7][2];
#pragma unroll
  for (int mt = 0; mt < 7; ++mt)
#pragma unroll
    for (int ks = 0; ks < 2; ++ks)
      kf[mt][ks] = *(const i32x4*)&Kl[mt * 16 + m][ks * 32 + quad * 8];

  for (int c = wv; c < 13; c += 4) {
    const int n0 = c * 16;
    const unsigned short* ap = ht + ((size_t)bt * 200 + n0 + m) * 64 + quad * 8;
    i32x4 a0 = *(const i32x4*)ap;
    i32x4 a1 = *(const i32x4*)(ap + 32);

    float s[7][4];
#pragma unroll
    for (int mt = 0; mt < 7; ++mt) {
      f32x4 acc = mfma_bf16(a0, kf[mt][0], (f32x4){0.f, 0.f, 0.f, 0.f});
      acc = mfma_bf16(a1, kf[mt][1], acc);
#pragma unroll
      for (int rg = 0; rg < 4; ++rg) s[mt][rg] = acc[rg];
    }
#pragma unroll
    for (int rg = 0; rg < 4; ++rg)
      s[6][rg] = (m < 4) ? s[6][rg] : -3.0e38f;   // keys 96..99 valid

    float S[4];
#pragma unroll
    for (int rg = 0; rg < 4; ++rg) {
      float mx = s[0][rg];
#pragma unroll
      for (int mt = 1; mt < 7; ++mt) mx = fmaxf(mx, s[mt][rg]);
#pragma unroll
      for (int msk = 1; msk < 16; msk <<= 1) mx = fmaxf(mx, __shfl_xor(mx, msk, 64));
      float sum = 0.f;
#pragma unroll
      for (int mt = 0; mt < 7; ++mt) {
        float p = __expf((s[mt][rg] - mx) * 0.125f);
        s[mt][rg] = p; sum += p;
      }
#pragma unroll
      for (int msk = 1; msk < 16; msk <<= 1) sum += __shfl_xor(sum, msk, 64);
      S[rg] = sum;
    }
    // P tile: cols 0..111 written, 112..127 re-zeroed (qt of prev iter)
#pragma unroll
    for (int rg = 0; rg < 4; ++rg) {
#pragma unroll
      for (int mt = 0; mt < 7; ++mt)
        PQ[wv][quad * 4 + rg][mt * 16 + m] = f2b(s[mt][rg]);
      PQ[wv][quad * 4 + rg][112 + m] = 0;
    }
    __builtin_amdgcn_s_waitcnt(0);

    i32x4 pa[4];
#pragma unroll
    for (int ks = 0; ks < 4; ++ks)
      pa[ks] = *(const i32x4*)&PQ[wv][m][ks * 32 + quad * 8];
    float rs[4];
#pragma unroll
    for (int rg = 0; rg < 4; ++rg) rs[rg] = __fdividef(1.0f, S[rg]);

    // PV -> x tile into XT (per-wave; never touches global)
#pragma unroll
    for (int ct = 0; ct < 4; ++ct) {
      f32x4 acc = {0.f, 0.f, 0.f, 0.f};
#pragma unroll
      for (int ks = 0; ks < 4; ++ks) {
        i32x4 b = *(const i32x4*)&VT2[ct * 16 + m][ks * 32 + quad * 8];
        acc = mfma_bf16(pa[ks], b, acc);
      }
#pragma unroll
      for (int rg = 0; rg < 4; ++rg)
        XT[wv][quad * 4 + rg][ct * 16 + m] = f2b(acc[rg] * rs[rg]);
    }
    __builtin_amdgcn_s_waitcnt(0);

    // qkv = x @ Wip^T + bip  (A from XT rows; identical math to old affine)
    i32x4 a0q = *(const i32x4*)&XT[wv][m][quad * 8];
    i32x4 a1q = *(const i32x4*)&XT[wv][m][32 + quad * 8];
#pragma unroll
    for (int g2 = 0; g2 < 3; ++g2) {
#pragma unroll
      for (int j = 0; j < 4; ++j) {
        int ct2 = g2 * 4 + j;
        const unsigned short* wp = Wip + (ct2 * 16 + m) * 64 + quad * 8;
        f32x4 acc = {0.f, 0.f, 0.f, 0.f};
        acc = mfma_bf16(a0q, *(const i32x4*)wp, acc);
        acc = mfma_bf16(a1q, *(const i32x4*)(wp + 32), acc);
        float bv = bip[ct2 * 16 + m];
#pragma unroll
        for (int rg = 0; rg < 4; ++rg)
          PQ[wv][quad * 4 + rg][ct2 * 16 + m] = f2b(acc[rg] + bv);
      }
    }
    __builtin_amdgcn_s_waitcnt(0);

    // flush qkv tile head-major: [h][row][q16|k16|v16], lane-consecutive
#pragma unroll
    for (int i = 0; i < 6; ++i) {
      int t = lane + i * 64;            // 0..383
      int h = t / 96, rem = t % 96;
      int row = rem / 6, col8 = rem % 6;
      int c_new = col8 * 8;
      int typ = c_new >> 4, cw = c_new & 15;
      int n = n0 + row;
      if (n < 200) {
        int c_std = typ * 64 + h * 16 + cw;
        i32x4 v = *(const i32x4*)&PQ[wv][row][c_std];
        *(i32x4*)(qkvh + (size_t)bt * 38400 + (size_t)h * 9600 +
                  (size_t)n * 48 + typ * 16 + cw) = v;
      }
    }
    __builtin_amdgcn_s_waitcnt(0);   // LDS reads done before next iter's P write
  }
}

// ---------------- K5: self attention (per bt,head block) -------------------
// qkvh head-major rows of 48: q(0..15)|k(16..31)|v(32..47). scores=q@k^T/4
// over hd=16; K padded 16->32 (A-quads 2,3 zero). XCD swizzle keeps the 4
// heads of a bt on one XCD for L2 sharing.
__global__ __launch_bounds__(256) void self_attn_k(
    const unsigned short* __restrict__ qkvh,  // [768][4][200][48]
    unsigned short* __restrict__ o) {         // [768*200][64]
  const int g = blockIdx.x;
  const int bt = ((g >> 5) << 3) | (g & 7);
  const int h = (g >> 3) & 3;
  const int tid = threadIdx.x;

  __shared__ __align__(16) unsigned short Kz[212][24];
  __shared__ __align__(16) unsigned short VT[16][232];
  __shared__ __align__(16) unsigned short P[4][16][232];

  const i32x4 z4 = {0, 0, 0, 0};
  {
    i32x4* p0 = (i32x4*)&Kz[0][0];
    for (int i = tid; i < 636; i += 256) p0[i] = z4;
    i32x4* p1 = (i32x4*)&VT[0][0];
    for (int i = tid; i < 464; i += 256) p1[i] = z4;
    i32x4* p2 = (i32x4*)&P[0][0][0];
    for (int i = tid; i < 1856; i += 256) p2[i] = z4;
  }
  __syncthreads();
  const unsigned short* base2 = qkvh + (size_t)bt * 38400 + (size_t)h * 9600;
  {
    for (int i = tid; i < 400; i += 256) {
      int r = i >> 1, half = (i & 1) * 8;
      *(i32x4*)&Kz[r][half] = *(const i32x4*)(base2 + (size_t)r * 48 + 16 + half);
      i32x4 vv = *(const i32x4*)(base2 + (size_t)r * 48 + 32 + half);
      unsigned short tmp[8];
      __builtin_memcpy(tmp, &vv, 16);
#pragma unroll
      for (int j = 0; j < 8; ++j) VT[half + j][r] = tmp[j];
    }
  }
  __syncthreads();

  const int lane = tid & 63, wv = tid >> 6;
  const int m = lane & 15, quad = lane >> 4;
  const bool kreal = quad < 2;

  i32x4 kf[13];
#pragma unroll
  for (int mt = 0; mt < 13; ++mt)
    kf[mt] = *(const i32x4*)&Kz[mt * 16 + m][quad * 8];

  for (int c = wv; c < 13; c += 4) {
    const int n0 = c * 16;
    i32x4 a = kreal ? *(const i32x4*)(base2 + (size_t)(n0 + m) * 48 + quad * 8) : z4;

    float s[13][4];
#pragma unroll
    for (int mt = 0; mt < 13; ++mt) {
      f32x4 acc = mfma_bf16(a, kf[mt], (f32x4){0.f, 0.f, 0.f, 0.f});
#pragma unroll
      for (int rg = 0; rg < 4; ++rg) s[mt][rg] = acc[rg];
    }
#pragma unroll
    for (int rg = 0; rg < 4; ++rg)
      s[12][rg] = (m < 8) ? s[12][rg] : -3.0e38f;   // keys 192..199 valid

    float S[4];
#pragma unroll
    for (int rg = 0; rg < 4; ++rg) {
      float mx = s[0][rg];
#pragma unroll
      for (int mt = 1; mt < 13; ++mt) mx = fmaxf(mx, s[mt][rg]);
#pragma unroll
      for (int msk = 1; msk < 16; msk <<= 1) mx = fmaxf(mx, __shfl_xor(mx, msk, 64));
      float sum = 0.f;
#pragma unroll
      for (int mt = 0; mt < 13; ++mt) {
        float p = __expf((s[mt][rg] - mx) * 0.25f);
        s[mt][rg] = p; sum += p;
      }
#pragma unroll
      for (int msk = 1; msk < 16; msk <<= 1) sum += __shfl_xor(sum, msk, 64);
      S[rg] = sum;
    }
#pragma unroll
    for (int mt = 0; mt < 13; ++mt)
#pragma unroll
      for (int rg = 0; rg < 4; ++rg)
        P[wv][quad * 4 + rg][mt * 16 + m] = f2b(s[mt][rg]);
    __builtin_amdgcn_s_waitcnt(0);

    f32x4 acc2 = {0.f, 0.f, 0.f, 0.f};
#pragma unroll
    for (int ks = 0; ks < 7; ++ks) {
      i32x4 pa = *(const i32x4*)&P[wv][m][ks * 32 + quad * 8];
      i32x4 vb2 = *(const i32x4*)&VT[m][ks * 32 + quad * 8];
      acc2 = mfma_bf16(pa, vb2, acc2);
    }
#pragma unroll
    for (int rg = 0; rg < 4; ++rg) {
      int n = n0 + quad * 4 + rg;
      if (n < 200)
        o[((size_t)bt * 200 + n) * 64 + h * 16 + m] = f2b(__fdividef(acc2[rg], S[rg]));
    }
  }
}

// ---------------- K6: fused attn_out + out_proj + residual -----------------
__global__ __launch_bounds__(256) void out_fused_k(
    const unsigned short* __restrict__ o,     // [153600][64] bf16
    const unsigned short* __restrict__ Wao,   // [64][64] bf16
    const float* __restrict__ bao,
    const unsigned short* __restrict__ Wop,   // [256][64] bf16
    const float* __restrict__ bop,
    const float* __restrict__ resid,          // [153600][256] f32
    float* __restrict__ out) {                // [153600][256] f32
  __shared__ __align__(16) unsigned short xs[64][72];
  __shared__ __align__(16) unsigned short as[64][72];
  __shared__ __align__(16) float Ls[4][16][68];
  const int tid = threadIdx.x;
  const long row0 = (long)blockIdx.x * 64;

  {
    const i32x4* xb = (const i32x4*)o + (size_t)row0 * 8;
    for (int i = tid; i < 512; i += 256) {
      int r = i >> 3, c = i & 7;
      *(i32x4*)&xs[r][c * 8] = xb[i];
    }
  }
  __syncthreads();

  const int lane = tid & 63, wv = tid >> 6;
  const int m = lane & 15, quad = lane >> 4;
  const int arow = wv * 16 + m;

  i32x4 af0 = *(const i32x4*)&xs[arow][quad * 8];
  i32x4 af1 = *(const i32x4*)&xs[arow][32 + quad * 8];

#pragma unroll
  for (int ct = 0; ct < 4; ++ct) {
    const unsigned short* wp = Wao + (ct * 16 + m) * 64 + quad * 8;
    f32x4 acc = {0.f, 0.f, 0.f, 0.f};
    acc = mfma_bf16(af0, *(const i32x4*)wp, acc);
    acc = mfma_bf16(af1, *(const i32x4*)(wp + 32), acc);
    float bv = bao[ct * 16 + m];
#pragma unroll
    for (int rg = 0; rg < 4; ++rg)
      as[wv * 16 + quad * 4 + rg][ct * 16 + m] = f2b(acc[rg] + bv);
  }
  __builtin_amdgcn_s_waitcnt(0);

  i32x4 bf0 = *(const i32x4*)&as[arow][quad * 8];
  i32x4 bf1 = *(const i32x4*)&as[arow][32 + quad * 8];

  const float4* residv = (const float4*)resid;
  float4* outv = (float4*)out;

  size_t gibase[4];
#pragma unroll
  for (int i = 0; i < 4; ++i) {
    int idx = lane + i * 64;
    int r = idx >> 4, c4 = idx & 15;
    gibase[i] = (size_t)(row0 + wv * 16 + r) * 64 + c4;
  }

#pragma unroll
  for (int cg = 0; cg < 4; ++cg) {
    float4 rv[4];
#pragma unroll
    for (int i = 0; i < 4; ++i) rv[i] = residv[gibase[i] + cg * 16];

#pragma unroll
    for (int c2 = 0; c2 < 4; ++c2) {
      int col = cg * 64 + c2 * 16 + m;
      const unsigned short* wp = Wop + col * 64 + quad * 8;
      f32x4 acc = {0.f, 0.f, 0.f, 0.f};
      acc = mfma_bf16(bf0, *(const i32x4*)wp, acc);
      acc = mfma_bf16(bf1, *(const i32x4*)(wp + 32), acc);
      float bv = bop[col];
#pragma unroll
      for (int rg = 0; rg < 4; ++rg)
        Ls[wv][quad * 4 + rg][c2 * 16 + m] = acc[rg] + bv;
    }
    __builtin_amdgcn_s_waitcnt(0);
#pragma unroll
    for (int i = 0; i < 4; ++i) {
      int idx = lane + i * 64;
      int r = idx >> 4, c4 = idx & 15;
      f32x4 sv = *(const f32x4*)&Ls[wv][r][c4 * 4];
      float4 ov;
      ov.x = sv[0] + rv[i].x; ov.y = sv[1] + rv[i].y;
      ov.z = sv[2] + rv[i].z; ov.w = sv[3] + rv[i].w;
      outv[gibase[i] + cg * 16] = ov;
    }
    __builtin_amdgcn_s_waitcnt(0);
  }
}

// ---------------- launch ----------------------------------------------------
extern "C" void kernel_launch(void* const* d_in, const int* in_sizes, int n_in,
                              void* d_out, int out_size, void* d_ws, size_t ws_size,
                              hipStream_t stream) {
  const float* turbine    = (const float*)d_in[0];
  const float* weather    = (const float*)d_in[1];
  const float* b_t_lin    = (const float*)d_in[3];
  const float* b_w_lin    = (const float*)d_in[5];
  const float* ln_t_g     = (const float*)d_in[6];
  const float* ln_t_b     = (const float*)d_in[7];
  const float* ln_w_g     = (const float*)d_in[8];
  const float* ln_w_b     = (const float*)d_in[9];
  const float* in_proj_b  = (const float*)d_in[11];
  const float* attn_out_b = (const float*)d_in[13];
  const float* out_proj_b = (const float*)d_in[15];

  unsigned short* ws  = (unsigned short*)d_ws;
  unsigned short* ht  = ws + 0;          //  9,830,400 (153600 x 64)
  unsigned short* hw  = ws + 9830400;    //  4,915,200 ( 76800 x 64)
  unsigned short* qkv = ws + 24576000;   // 29,491,200 (768 x 4 x 200 x 48)
  unsigned short* o   = ws + 0;          // alias ht (dead after cross_qkv)
  unsigned short* wb  = ws + 54067200;   // 65,536 bf16 weights
  unsigned short* wtb = wb;
  unsigned short* wwb = wb + 16384;
  unsigned short* ipb = wb + 32768;
  unsigned short* aob = wb + 45056;
  unsigned short* opb = wb + 49152;

  cvt_weights_k<<<256, 256, 0, stream>>>((const float*)d_in[2], (const float*)d_in[4],
                                         (const float*)d_in[10], (const float*)d_in[12],
                                         (const float*)d_in[14], wb);
  ln_affine_k<256><<<2400, 256, 0, stream>>>(
      turbine, wtb, b_t_lin, ln_t_g, ln_t_b, ht);
  ln_affine_k<256><<<1200, 256, 0, stream>>>(
      weather, wwb, b_w_lin, ln_w_g, ln_w_b, hw);
  cross_qkv_k<<<768, 256, 0, stream>>>(ht, hw, ipb, in_proj_b, qkv);
  self_attn_k<<<3072, 256, 0, stream>>>(qkv, o);
  out_fused_k<<<2400, 256, 0, stream>>>(
      o, aob, attn_out_b, opb, out_proj_b, turbine, (float*)d_out);
}